// Round 2
// baseline (390.206 us; speedup 1.0000x reference)
//
#include <hip/hip_runtime.h>
#include <stdint.h>

#define NIMG 8
#define NCLS 80
#define HF 100
#define WF 152
#define NPTS (HF*WF)          // 15200
#define NPC (NPTS*NCLS)       // 1216000
#define NG (NPC/4)            // 304000 float4 groups per image
#define GPB 512               // groups per block (256 thr x 2)
#define SCANB ((NG + GPB - 1) / GPB)   // 594
#define TOPK 1000
#define CAP 2048
#define POSTK 100

// ---- workspace layout (bytes) ----
static constexpr size_t B_H1    = 0;                           // u32 [8][4096]
static constexpr size_t B_CNT   = B_H1 + (size_t)8*4096*4;     // u32 [8]
static constexpr size_t B_META  = B_CNT + 8*4;                 // u32 [8][4] {c_above,B,-,-}
static constexpr size_t B_ZEND  = B_META + 8*4*4;              // memset 0 through here
static constexpr size_t B_SIGC  = (B_ZEND + 15) & ~(size_t)15; // f32 [8][NPTS] sigmoid(ctr)
static constexpr size_t B_CAND  = B_SIGC + (size_t)8*NPTS*4;   // u64 [8][CAP]
static constexpr size_t B_BOX   = B_CAND + (size_t)8*CAP*8;    // f32 [8][TOPK][4]
static constexpr size_t B_OBOX  = B_BOX + (size_t)8*TOPK*16;   // f32 [8][TOPK][4]
static constexpr size_t B_SC    = B_OBOX + (size_t)8*TOPK*16;  // f32 [8][TOPK]
static constexpr size_t B_VAL   = B_SC + (size_t)8*TOPK*4;     // u32 [8][TOPK]
static constexpr size_t B_LAB   = B_VAL + (size_t)8*TOPK*4;    // u32 [8][TOPK]
static constexpr size_t B_CBASE = B_LAB + (size_t)8*TOPK*4;    // u32 [8][81]
static constexpr size_t B_CLIST = B_CBASE + (size_t)8*81*4;    // u32 [8][TOPK]
static constexpr size_t B_KEEP  = B_CLIST + (size_t)8*TOPK*4;  // u32 [8][TOPK]

__device__ __forceinline__ float sigm(float x){ return 1.0f / (1.0f + expf(-x)); }

// precompute sigmoid(centerness) per point -> ws (exact same formula as scans)
__global__ void k_prep(const float* __restrict__ ctr, float* __restrict__ sigc){
  int i = blockIdx.x * 256 + threadIdx.x;
  if (i < NIMG * NPTS) sigc[i] = sigm(ctr[i]);
}

// pass 1: level-1 histogram of score bits>>20 (4096 bins), float4-vectorized
__global__ void __launch_bounds__(256)
k_hist(const float* __restrict__ box_cls, const float* __restrict__ sigc,
       uint32_t* __restrict__ h1){
  __shared__ uint32_t h[4096];
  for (int i = threadIdx.x; i < 4096; i += 256) h[i] = 0;
  __syncthreads();
  const int n = blockIdx.y;
  const float4* cls4 = (const float4*)(box_cls + (size_t)n * NPC);
  const float* sc_im = sigc + (size_t)n * NPTS;
  const int g0 = blockIdx.x * GPB + threadIdx.x;
  const int g1 = g0 + 256;
  // issue all 4 loads up front (addresses are data-independent)
  float4 x0, x1, s0, s1;
  bool v0 = (g0 < NG), v1 = (g1 < NG);
  int p0 = 0, p1 = 0;
  if (v0){ int e = g0 * 4; int c = e / NPTS; p0 = e - c * NPTS; x0 = cls4[g0];
           s0 = *(const float4*)(sc_im + p0); }
  if (v1){ int e = g1 * 4; int c = e / NPTS; p1 = e - c * NPTS; x1 = cls4[g1];
           s1 = *(const float4*)(sc_im + p1); }
  auto acc1 = [&](float x, float sc){
    float scls = sigm(x);
    if (scls > 0.05f){
      float s = scls * sc;
      if (s > 0.0f) atomicAdd(&h[__float_as_uint(s) >> 20], 1u);
    }
  };
  if (v0){ acc1(x0.x, s0.x); acc1(x0.y, s0.y); acc1(x0.z, s0.z); acc1(x0.w, s0.w); }
  if (v1){ acc1(x1.x, s1.x); acc1(x1.y, s1.y); acc1(x1.z, s1.z); acc1(x1.w, s1.w); }
  __syncthreads();
  uint32_t* g = h1 + (size_t)n * 4096;
  for (int i = threadIdx.x; i < 4096; i += 256){
    uint32_t v = h[i];
    if (v) atomicAdd(&g[i], v);
  }
}

// find boundary bin B: count(bins > B) < TOPK <= count(bins >= B)
__global__ void k_scan1(const uint32_t* __restrict__ h1, uint32_t* __restrict__ meta){
  const int n = blockIdx.x;
  const uint32_t* h = h1 + (size_t)n * 4096;
  __shared__ uint32_t psum[256];
  __shared__ uint32_t suff[256];
  const int t = threadIdx.x;
  uint32_t s = 0;
  #pragma unroll
  for (int i = 0; i < 16; ++i) s += h[t * 16 + i];
  psum[t] = s;
  __syncthreads();
  if (t == 0){
    uint32_t acc = 0;
    for (int seg = 255; seg >= 0; --seg){ suff[seg] = acc; acc += psum[seg]; }
  }
  __syncthreads();
  if (suff[t] < TOPK && suff[t] + psum[t] >= TOPK){
    uint32_t acc = suff[t];
    for (int b = t * 16 + 15; b >= t * 16; --b){
      uint32_t hb = h[b];
      if (acc + hb >= TOPK){
        meta[n * 4 + 0] = acc;           // c_above
        meta[n * 4 + 1] = (uint32_t)b;   // B
        break;
      }
      acc += hb;
    }
  }
}

// pass 2: recompute scores (identical bits), collect all with prefix12 >= B
__global__ void __launch_bounds__(256)
k_collect(const float* __restrict__ box_cls, const float* __restrict__ sigc,
          const uint32_t* __restrict__ meta,
          uint32_t* __restrict__ cnt, uint64_t* __restrict__ cand){
  const int n = blockIdx.y;
  const uint32_t B = meta[n * 4 + 1];
  const float4* cls4 = (const float4*)(box_cls + (size_t)n * NPC);
  const float* sc_im = sigc + (size_t)n * NPTS;
  uint64_t* cd = cand + (size_t)n * CAP;
  const int g0 = blockIdx.x * GPB + threadIdx.x;
  const int g1 = g0 + 256;
  float4 x0, x1, s0, s1;
  bool v0 = (g0 < NG), v1 = (g1 < NG);
  int p0 = 0, c0 = 0, p1 = 0, c1 = 0;
  if (v0){ int e = g0 * 4; c0 = e / NPTS; p0 = e - c0 * NPTS; x0 = cls4[g0];
           s0 = *(const float4*)(sc_im + p0); }
  if (v1){ int e = g1 * 4; c1 = e / NPTS; p1 = e - c1 * NPTS; x1 = cls4[g1];
           s1 = *(const float4*)(sc_im + p1); }
  auto coll1 = [&](float x, float sc, int p, int c){
    float scls = sigm(x);
    if (scls > 0.05f){
      float s = scls * sc;
      if (s > 0.0f){
        uint32_t bits = __float_as_uint(s);
        if ((bits >> 20) >= B){
          uint32_t f = (uint32_t)(p * NCLS + c);
          uint32_t pos = atomicAdd(&cnt[n], 1u);
          if (pos < CAP)
            cd[pos] = ((uint64_t)bits << 32) | (uint64_t)(0xFFFFFFFFu - f);
        }
      }
    }
  };
  if (v0){ coll1(x0.x, s0.x, p0 + 0, c0); coll1(x0.y, s0.y, p0 + 1, c0);
           coll1(x0.z, s0.z, p0 + 2, c0); coll1(x0.w, s0.w, p0 + 3, c0); }
  if (v1){ coll1(x1.x, s1.x, p1 + 0, c1); coll1(x1.y, s1.y, p1 + 1, c1);
           coll1(x1.z, s1.z, p1 + 2, c1); coll1(x1.w, s1.w, p1 + 3, c1); }
}

// sort candidates (value desc, index asc), take top-1000, decode boxes
__global__ void __launch_bounds__(1024)
k_sort_decode(const uint32_t* __restrict__ cnt, const uint64_t* __restrict__ cand,
              const float* __restrict__ locations, const float* __restrict__ box_reg,
              const float* __restrict__ im_info,
              float* __restrict__ boxw, float* __restrict__ oboxw, float* __restrict__ scw,
              uint32_t* __restrict__ valw, uint32_t* __restrict__ labw){
  __shared__ uint64_t key[2048];
  const int n = blockIdx.x;
  const int t = threadIdx.x;
  int nc = (int)cnt[n]; if (nc > CAP) nc = CAP;
  const uint64_t* cd = cand + (size_t)n * CAP;
  key[t]        = (t < nc) ? cd[t] : 0ull;
  key[t + 1024] = (t + 1024 < nc) ? cd[t + 1024] : 0ull;
  __syncthreads();
  for (int k = 2; k <= 2048; k <<= 1){
    for (int j = k >> 1; j > 0; j >>= 1){
      #pragma unroll
      for (int m = 0; m < 2; ++m){
        int i = t + m * 1024;
        int ixj = i ^ j;
        if (ixj > i){
          uint64_t a = key[i], b = key[ixj];
          bool desc = ((i & k) == 0);
          bool sw = desc ? (a < b) : (a > b);
          if (sw){ key[i] = b; key[ixj] = a; }
        }
      }
      __syncthreads();
    }
  }
  if (t < TOPK){
    uint64_t kk = key[t];
    uint32_t bits = (uint32_t)(kk >> 32);
    uint32_t fi = 0xFFFFFFFFu - (uint32_t)(kk & 0xFFFFFFFFull);
    float v = __uint_as_float(bits);
    int loc = 0, ci = 0;
    if (v > 0.0f){ loc = (int)(fi / NCLS); ci = (int)(fi - (uint32_t)loc * NCLS); }
    float px = locations[2 * loc], py = locations[2 * loc + 1];
    const float* rg = box_reg + (size_t)n * 4 * NPTS;
    float rl = rg[loc], rt = rg[NPTS + loc], rr = rg[2 * NPTS + loc], rb = rg[3 * NPTS + loc];
    float h_im = im_info[n * 2 + 0], w_im = im_info[n * 2 + 1];
    float x1 = fminf(fmaxf(px - rl, 0.0f), w_im - 1.0f);
    float y1 = fminf(fmaxf(py - rt, 0.0f), h_im - 1.0f);
    float x2 = fminf(fmaxf(px + rr, 0.0f), w_im - 1.0f);
    float y2 = fminf(fmaxf(py + rb, 0.0f), h_im - 1.0f);
    bool valid = (v > 0.0f) && (__fsub_rn(x2, x1) >= 0.0f) && (__fsub_rn(y2, y1) >= 0.0f);
    float scv = valid ? v : 0.0f;
    float lab = (float)(ci + 1);
    float off = __fmul_rn(lab, 100000.0f);   // CLASS_OFFSET, mul then add (no fma) like ref
    size_t b4 = ((size_t)n * TOPK + t) * 4;
    boxw[b4 + 0] = x1; boxw[b4 + 1] = y1; boxw[b4 + 2] = x2; boxw[b4 + 3] = y2;
    oboxw[b4 + 0] = __fadd_rn(x1, off); oboxw[b4 + 1] = __fadd_rn(y1, off);
    oboxw[b4 + 2] = __fadd_rn(x2, off); oboxw[b4 + 3] = __fadd_rn(y2, off);
    size_t b1 = (size_t)n * TOPK + t;
    scw[b1] = scv; valw[b1] = valid ? 1u : 0u; labw[b1] = (uint32_t)(ci + 1);
  }
}

// stable partition of the 1000 sorted candidates by class label
__global__ void k_partition(const uint32_t* __restrict__ labw,
                            uint32_t* __restrict__ cbase, uint32_t* __restrict__ clist){
  const int n = blockIdx.x;
  __shared__ uint8_t lab_s[TOPK];
  __shared__ uint32_t cnt_s[NCLS];
  __shared__ uint32_t base_s[NCLS + 1];
  const int t = threadIdx.x;
  for (int i = t; i < NCLS; i += 256) cnt_s[i] = 0;
  __syncthreads();
  for (int i = t; i < TOPK; i += 256){
    uint8_t l = (uint8_t)(labw[n * TOPK + i] - 1);
    lab_s[i] = l;
    atomicAdd(&cnt_s[l], 1u);
  }
  __syncthreads();
  if (t == 0){
    uint32_t acc = 0;
    for (int c = 0; c < NCLS; ++c){ base_s[c] = acc; acc += cnt_s[c]; }
    base_s[NCLS] = acc;
  }
  __syncthreads();
  for (int i = t; i < TOPK; i += 256){
    uint8_t my = lab_s[i];
    uint32_t rank = 0;
    for (int j = 0; j < i; ++j) rank += (lab_s[j] == my) ? 1u : 0u;
    clist[n * TOPK + base_s[my] + rank] = (uint32_t)i;
  }
  for (int i = t; i < NCLS + 1; i += 256) cbase[n * (NCLS + 1) + i] = base_s[i];
}

// greedy NMS per (image,class); cross-class IoU is exactly 0 under the 1e5 offset
__global__ void __launch_bounds__(64)
k_nms(const uint32_t* __restrict__ cbase, const uint32_t* __restrict__ clist,
      const float* __restrict__ oboxw, const uint32_t* __restrict__ valw,
      uint32_t* __restrict__ keepw){
  const int n = blockIdx.y;
  const int c = blockIdx.x;
  const uint32_t base = cbase[n * (NCLS + 1) + c];
  const uint32_t kcnt = cbase[n * (NCLS + 1) + c + 1] - base;
  if (kcnt == 0) return;
  const int L = threadIdx.x;
  const uint32_t* lst = clist + (size_t)n * TOPK + base;
  if (kcnt <= 64){
    int gi = 0, kp = 0;
    float b0 = 0, b1 = 0, b2 = 0, b3 = 0, ar = 0;
    if (L < (int)kcnt){
      gi = (int)lst[L];
      size_t a4 = ((size_t)n * TOPK + gi) * 4;
      b0 = oboxw[a4 + 0]; b1 = oboxw[a4 + 1]; b2 = oboxw[a4 + 2]; b3 = oboxw[a4 + 3];
      kp = (valw[n * TOPK + gi] != 0) ? 1 : 0;
      ar = __fmul_rn(fmaxf(__fsub_rn(b2, b0), 0.0f), fmaxf(__fsub_rn(b3, b1), 0.0f));
    }
    for (int i = 0; i + 1 < (int)kcnt; ++i){
      int alive = __shfl(kp, i);
      float xi0 = __shfl(b0, i), xi1 = __shfl(b1, i), xi2 = __shfl(b2, i), xi3 = __shfl(b3, i);
      float ai = __shfl(ar, i);
      if (alive && L > i && kp){
        float ltx = fmaxf(xi0, b0), lty = fmaxf(xi1, b1);
        float rbx = fminf(xi2, b2), rby = fminf(xi3, b3);
        float w = fmaxf(__fsub_rn(rbx, ltx), 0.0f);
        float h = fmaxf(__fsub_rn(rby, lty), 0.0f);
        float inter = __fmul_rn(w, h);
        float den = __fadd_rn(__fsub_rn(__fadd_rn(ai, ar), inter), 1e-9f);
        if (inter / den > 0.6f) kp = 0;
      }
    }
    if (L < (int)kcnt) keepw[n * TOPK + gi] = (uint32_t)kp;
  } else if (L == 0){
    // slow path (kcnt > 64): sequential, correctness-only (statistically never hit)
    for (uint32_t i = 0; i < kcnt; ++i){
      int gi = (int)lst[i];
      keepw[n * TOPK + gi] = valw[n * TOPK + gi];
    }
    for (uint32_t i = 0; i < kcnt; ++i){
      int gi = (int)lst[i];
      if (!keepw[n * TOPK + gi]) continue;
      size_t a4 = ((size_t)n * TOPK + gi) * 4;
      float x0 = oboxw[a4], x1 = oboxw[a4 + 1], x2 = oboxw[a4 + 2], x3 = oboxw[a4 + 3];
      float ai = __fmul_rn(fmaxf(__fsub_rn(x2, x0), 0.0f), fmaxf(__fsub_rn(x3, x1), 0.0f));
      for (uint32_t j = i + 1; j < kcnt; ++j){
        int gj = (int)lst[j];
        if (!keepw[n * TOPK + gj]) continue;
        size_t c4 = ((size_t)n * TOPK + gj) * 4;
        float y0 = oboxw[c4], y1 = oboxw[c4 + 1], y2 = oboxw[c4 + 2], y3 = oboxw[c4 + 3];
        float aj = __fmul_rn(fmaxf(__fsub_rn(y2, y0), 0.0f), fmaxf(__fsub_rn(y3, y1), 0.0f));
        float ltx = fmaxf(x0, y0), lty = fmaxf(x1, y1);
        float rbx = fminf(x2, y2), rby = fminf(x3, y3);
        float w = fmaxf(__fsub_rn(rbx, ltx), 0.0f);
        float h = fmaxf(__fsub_rn(rby, lty), 0.0f);
        float inter = __fmul_rn(w, h);
        float den = __fadd_rn(__fsub_rn(__fadd_rn(ai, aj), inter), 1e-9f);
        if (inter / den > 0.6f) keepw[n * TOPK + gj] = 0;
      }
    }
  }
}

// compact kept (already score-sorted) entries; first 100 rows, rest zero
__global__ void k_final(const uint32_t* __restrict__ keepw, const float* __restrict__ boxw,
                        const uint32_t* __restrict__ labw, const float* __restrict__ scw,
                        float* __restrict__ out){
  const int n = blockIdx.x;
  __shared__ int fi_s[POSTK];
  __shared__ int cnt_s;
  if (threadIdx.x == 0){
    int cnt = 0;
    for (int i = 0; i < TOPK && cnt < POSTK; ++i)
      if (keepw[n * TOPK + i]) fi_s[cnt++] = i;
    cnt_s = cnt;
  }
  __syncthreads();
  const int t = threadIdx.x;
  if (t < POSTK){
    float* row = out + ((size_t)n * POSTK + t) * 6;
    if (t < cnt_s){
      int i = fi_s[t];
      size_t b4 = ((size_t)n * TOPK + i) * 4;
      row[0] = boxw[b4]; row[1] = boxw[b4 + 1]; row[2] = boxw[b4 + 2]; row[3] = boxw[b4 + 3];
      row[4] = (float)labw[n * TOPK + i]; row[5] = scw[n * TOPK + i];
    } else {
      row[0] = 0.0f; row[1] = 0.0f; row[2] = 0.0f;
      row[3] = 0.0f; row[4] = 0.0f; row[5] = 0.0f;
    }
  }
}

extern "C" void kernel_launch(void* const* d_in, const int* in_sizes, int n_in,
                              void* d_out, int out_size, void* d_ws, size_t ws_size,
                              hipStream_t stream){
  const float* locations = (const float*)d_in[0];
  const float* box_cls   = (const float*)d_in[1];
  const float* box_reg   = (const float*)d_in[2];
  const float* ctr       = (const float*)d_in[3];
  const float* im_info   = (const float*)d_in[4];
  float* out = (float*)d_out;
  char* ws = (char*)d_ws;
  uint32_t* h1    = (uint32_t*)(ws + B_H1);
  uint32_t* cnt   = (uint32_t*)(ws + B_CNT);
  uint32_t* meta  = (uint32_t*)(ws + B_META);
  float*    sigc  = (float*)(ws + B_SIGC);
  uint64_t* cand  = (uint64_t*)(ws + B_CAND);
  float*    boxw  = (float*)(ws + B_BOX);
  float*    oboxw = (float*)(ws + B_OBOX);
  float*    scw   = (float*)(ws + B_SC);
  uint32_t* valw  = (uint32_t*)(ws + B_VAL);
  uint32_t* labw  = (uint32_t*)(ws + B_LAB);
  uint32_t* cbase = (uint32_t*)(ws + B_CBASE);
  uint32_t* clist = (uint32_t*)(ws + B_CLIST);
  uint32_t* keepw = (uint32_t*)(ws + B_KEEP);

  hipMemsetAsync(d_ws, 0, B_ZEND, stream);
  k_prep<<<(NIMG * NPTS + 255) / 256, 256, 0, stream>>>(ctr, sigc);
  dim3 scang(SCANB, NIMG);
  k_hist<<<scang, 256, 0, stream>>>(box_cls, sigc, h1);
  k_scan1<<<NIMG, 256, 0, stream>>>(h1, meta);
  k_collect<<<scang, 256, 0, stream>>>(box_cls, sigc, meta, cnt, cand);
  k_sort_decode<<<NIMG, 1024, 0, stream>>>(cnt, cand, locations, box_reg, im_info,
                                           boxw, oboxw, scw, valw, labw);
  k_partition<<<NIMG, 256, 0, stream>>>(labw, cbase, clist);
  k_nms<<<dim3(NCLS, NIMG), 64, 0, stream>>>(cbase, clist, oboxw, valw, keepw);
  k_final<<<NIMG, 128, 0, stream>>>(keepw, boxw, labw, scw, out);
}

// Round 3
// 384.395 us; speedup vs baseline: 1.0151x; 1.0151x over previous
//
#include <hip/hip_runtime.h>
#include <stdint.h>

#define NIMG 8
#define NCLS 80
#define HF 100
#define WF 152
#define NPTS (HF*WF)          // 15200
#define NPC (NPTS*NCLS)       // 1216000
#define NG (NPC/4)            // 304000 float4 groups per image
#define GPB 2048              // groups per block (256 thr x 8)
#define BPI ((NG + GPB - 1) / GPB)   // 149 blocks per image
#define TOPK 1000
#define CAP 2048
#define POSTK 100

// ---- workspace layout (bytes) ----
static constexpr size_t B_H1    = 0;                           // u32 [8][4096]
static constexpr size_t B_CNT   = B_H1 + (size_t)8*4096*4;     // u32 [8]
static constexpr size_t B_DONE  = B_CNT + 8*4;                 // u32 [8]
static constexpr size_t B_META  = B_DONE + 8*4;                // u32 [8][4] {c_above,B,-,-}
static constexpr size_t B_ZEND  = B_META + 8*4*4;              // memset 0 through here
static constexpr size_t B_SIGC  = (B_ZEND + 15) & ~(size_t)15; // f32 [8][NPTS] sigmoid(ctr)
static constexpr size_t B_CAND  = B_SIGC + (size_t)8*NPTS*4;   // u64 [8][CAP]
static constexpr size_t B_BOX   = B_CAND + (size_t)8*CAP*8;    // f32 [8][TOPK][4]
static constexpr size_t B_OBOX  = B_BOX + (size_t)8*TOPK*16;   // f32 [8][TOPK][4]
static constexpr size_t B_SC    = B_OBOX + (size_t)8*TOPK*16;  // f32 [8][TOPK]
static constexpr size_t B_VAL   = B_SC + (size_t)8*TOPK*4;     // u32 [8][TOPK]
static constexpr size_t B_LAB   = B_VAL + (size_t)8*TOPK*4;    // u32 [8][TOPK]
static constexpr size_t B_KEEP  = B_LAB + (size_t)8*TOPK*4;    // u32 [8][TOPK]

__device__ __forceinline__ float sigm(float x){ return 1.0f / (1.0f + expf(-x)); }

// precompute sigmoid(centerness) per point (exact same formula as scans)
__global__ void k_prep(const float* __restrict__ ctr, float* __restrict__ sigc){
  int i = blockIdx.x * 256 + threadIdx.x;
  if (i < NIMG * NPTS) sigc[i] = sigm(ctr[i]);
}

// pass 1: 4096-bin histogram of score bits>>20; last block per image finds boundary bin
__global__ void __launch_bounds__(256)
k_hist(const float* __restrict__ box_cls, const float* __restrict__ sigc,
       uint32_t* __restrict__ h1, uint32_t* __restrict__ done, uint32_t* __restrict__ meta){
  __shared__ uint32_t h[4096];
  for (int i = threadIdx.x; i < 4096; i += 256) h[i] = 0;
  __syncthreads();
  const int n = blockIdx.y;
  const int tid = threadIdx.x;
  const float4* cls4 = (const float4*)(box_cls + (size_t)n * NPC);
  const float* sc_im = sigc + (size_t)n * NPTS;
  // 8 groups/thread, all loads issued up front, unconditional (clamped)
  float4 xc[8], xs[8];
  bool ok[8];
  #pragma unroll
  for (int j = 0; j < 8; ++j){
    int graw = blockIdx.x * GPB + j * 256 + tid;
    ok[j] = (graw < NG);
    int g = ok[j] ? graw : (NG - 1);
    xc[j] = cls4[g];
    int e = g * 4; int c = e / NPTS; int p = e - c * NPTS;
    xs[j] = *(const float4*)(sc_im + p);
  }
  #pragma unroll
  for (int j = 0; j < 8; ++j){
    if (ok[j]){
      float sx[4] = {xc[j].x, xc[j].y, xc[j].z, xc[j].w};
      float cx[4] = {xs[j].x, xs[j].y, xs[j].z, xs[j].w};
      #pragma unroll
      for (int q = 0; q < 4; ++q){
        float scls = sigm(sx[q]);
        if (scls > 0.05f){
          float s = scls * cx[q];
          if (s > 0.0f) atomicAdd(&h[__float_as_uint(s) >> 20], 1u);
        }
      }
    }
  }
  __syncthreads();
  uint32_t* g1 = h1 + (size_t)n * 4096;
  for (int i = tid; i < 4096; i += 256){
    uint32_t v = h[i];
    if (v) atomicAdd(&g1[i], v);
  }
  // ---- fused boundary-bin scan: last finishing block of this image ----
  __threadfence();
  __shared__ uint32_t last;
  if (tid == 0){
    uint32_t prev = __hip_atomic_fetch_add(&done[n], 1u, __ATOMIC_ACQ_REL,
                                           __HIP_MEMORY_SCOPE_AGENT);
    last = (prev == (uint32_t)(BPI - 1)) ? 1u : 0u;
  }
  __syncthreads();
  if (!last) return;
  __shared__ uint32_t psum[256];
  __shared__ uint32_t suff[256];
  uint32_t hv[16];
  uint32_t s = 0;
  #pragma unroll
  for (int i = 0; i < 16; ++i){
    hv[i] = __hip_atomic_load(&g1[tid * 16 + i], __ATOMIC_RELAXED, __HIP_MEMORY_SCOPE_AGENT);
    s += hv[i];
  }
  psum[tid] = s;
  __syncthreads();
  if (tid == 0){
    uint32_t a = 0;
    for (int seg = 255; seg >= 0; --seg){ suff[seg] = a; a += psum[seg]; }
  }
  __syncthreads();
  if (suff[tid] < TOPK && suff[tid] + psum[tid] >= TOPK){
    uint32_t a = suff[tid];
    for (int b = 15; b >= 0; --b){
      uint32_t hb = hv[b];
      if (a + hb >= TOPK){
        meta[n * 4 + 0] = a;                       // c_above
        meta[n * 4 + 1] = (uint32_t)(tid * 16 + b); // boundary bin B
        break;
      }
      a += hb;
    }
  }
}

// pass 2: recompute scores (identical bits), collect all with prefix12 >= B
__global__ void __launch_bounds__(256)
k_collect(const float* __restrict__ box_cls, const float* __restrict__ sigc,
          const uint32_t* __restrict__ meta,
          uint32_t* __restrict__ cnt, uint64_t* __restrict__ cand){
  const int n = blockIdx.y;
  const int tid = threadIdx.x;
  const uint32_t B = meta[n * 4 + 1];
  const float4* cls4 = (const float4*)(box_cls + (size_t)n * NPC);
  const float* sc_im = sigc + (size_t)n * NPTS;
  uint64_t* cd = cand + (size_t)n * CAP;
  float4 xc[8], xs[8];
  bool ok[8];
  int pp[8], cc[8];
  #pragma unroll
  for (int j = 0; j < 8; ++j){
    int graw = blockIdx.x * GPB + j * 256 + tid;
    ok[j] = (graw < NG);
    int g = ok[j] ? graw : (NG - 1);
    xc[j] = cls4[g];
    int e = g * 4; int c = e / NPTS; int p = e - c * NPTS;
    pp[j] = p; cc[j] = c;
    xs[j] = *(const float4*)(sc_im + p);
  }
  #pragma unroll
  for (int j = 0; j < 8; ++j){
    if (ok[j]){
      float sx[4] = {xc[j].x, xc[j].y, xc[j].z, xc[j].w};
      float cx[4] = {xs[j].x, xs[j].y, xs[j].z, xs[j].w};
      #pragma unroll
      for (int q = 0; q < 4; ++q){
        float scls = sigm(sx[q]);
        if (scls > 0.05f){
          float s = scls * cx[q];
          if (s > 0.0f){
            uint32_t bits = __float_as_uint(s);
            if ((bits >> 20) >= B){
              uint32_t f = (uint32_t)((pp[j] + q) * NCLS + cc[j]);
              uint32_t pos = atomicAdd(&cnt[n], 1u);
              if (pos < CAP)
                cd[pos] = ((uint64_t)bits << 32) | (uint64_t)(0xFFFFFFFFu - f);
            }
          }
        }
      }
    }
  }
}

// sort candidates (value desc, index asc), take top-1000, decode boxes
__global__ void __launch_bounds__(1024)
k_sort_decode(const uint32_t* __restrict__ cnt, const uint64_t* __restrict__ cand,
              const float* __restrict__ locations, const float* __restrict__ box_reg,
              const float* __restrict__ im_info,
              float* __restrict__ boxw, float* __restrict__ oboxw, float* __restrict__ scw,
              uint32_t* __restrict__ valw, uint32_t* __restrict__ labw){
  __shared__ uint64_t key[2048];
  const int n = blockIdx.x;
  const int t = threadIdx.x;
  int nc = (int)cnt[n]; if (nc > CAP) nc = CAP;
  const uint64_t* cd = cand + (size_t)n * CAP;
  key[t]        = (t < nc) ? cd[t] : 0ull;
  key[t + 1024] = (t + 1024 < nc) ? cd[t + 1024] : 0ull;
  __syncthreads();
  for (int k = 2; k <= 2048; k <<= 1){
    for (int j = k >> 1; j > 0; j >>= 1){
      #pragma unroll
      for (int m = 0; m < 2; ++m){
        int i = t + m * 1024;
        int ixj = i ^ j;
        if (ixj > i){
          uint64_t a = key[i], b = key[ixj];
          bool desc = ((i & k) == 0);
          bool sw = desc ? (a < b) : (a > b);
          if (sw){ key[i] = b; key[ixj] = a; }
        }
      }
      __syncthreads();
    }
  }
  if (t < TOPK){
    uint64_t kk = key[t];
    uint32_t bits = (uint32_t)(kk >> 32);
    uint32_t fi = 0xFFFFFFFFu - (uint32_t)(kk & 0xFFFFFFFFull);
    float v = __uint_as_float(bits);
    int loc = 0, ci = 0;
    if (v > 0.0f){ loc = (int)(fi / NCLS); ci = (int)(fi - (uint32_t)loc * NCLS); }
    float px = locations[2 * loc], py = locations[2 * loc + 1];
    const float* rg = box_reg + (size_t)n * 4 * NPTS;
    float rl = rg[loc], rt = rg[NPTS + loc], rr = rg[2 * NPTS + loc], rb = rg[3 * NPTS + loc];
    float h_im = im_info[n * 2 + 0], w_im = im_info[n * 2 + 1];
    float x1 = fminf(fmaxf(px - rl, 0.0f), w_im - 1.0f);
    float y1 = fminf(fmaxf(py - rt, 0.0f), h_im - 1.0f);
    float x2 = fminf(fmaxf(px + rr, 0.0f), w_im - 1.0f);
    float y2 = fminf(fmaxf(py + rb, 0.0f), h_im - 1.0f);
    bool valid = (v > 0.0f) && (__fsub_rn(x2, x1) >= 0.0f) && (__fsub_rn(y2, y1) >= 0.0f);
    float scv = valid ? v : 0.0f;
    float lab = (float)(ci + 1);
    float off = __fmul_rn(lab, 100000.0f);   // CLASS_OFFSET, mul then add (no fma) like ref
    size_t b4 = ((size_t)n * TOPK + t) * 4;
    boxw[b4 + 0] = x1; boxw[b4 + 1] = y1; boxw[b4 + 2] = x2; boxw[b4 + 3] = y2;
    oboxw[b4 + 0] = __fadd_rn(x1, off); oboxw[b4 + 1] = __fadd_rn(y1, off);
    oboxw[b4 + 2] = __fadd_rn(x2, off); oboxw[b4 + 3] = __fadd_rn(y2, off);
    size_t b1 = (size_t)n * TOPK + t;
    scw[b1] = scv; valw[b1] = valid ? 1u : 0u; labw[b1] = (uint32_t)(ci + 1);
  }
}

// greedy NMS per (image,class); each block gathers its class's indices by ballot
__global__ void __launch_bounds__(64)
k_nms(const uint32_t* __restrict__ labw, const float* __restrict__ oboxw,
      const uint32_t* __restrict__ valw, uint32_t* __restrict__ keepw){
  const int n = blockIdx.y;
  const int c = blockIdx.x;
  const int L = threadIdx.x;
  __shared__ uint16_t list[TOPK];
  const uint32_t* lw = labw + (size_t)n * TOPK;
  uint32_t run = 0;
  #pragma unroll
  for (int j = 0; j < (TOPK + 63) / 64; ++j){
    int idx = j * 64 + L;
    bool m = (idx < TOPK) && (lw[idx] == (uint32_t)(c + 1));
    unsigned long long mask = __ballot(m);
    if (m){
      int pos = (int)run + __popcll(mask & ((1ull << L) - 1ull));
      list[pos] = (uint16_t)idx;
    }
    run += (uint32_t)__popcll(mask);
  }
  __syncthreads();
  const uint32_t kcnt = run;   // uniform across the wave
  if (kcnt == 0) return;
  if (kcnt <= 64){
    int gi = 0, kp = 0;
    float b0 = 0, b1 = 0, b2 = 0, b3 = 0, ar = 0;
    if (L < (int)kcnt){
      gi = (int)list[L];
      size_t a4 = ((size_t)n * TOPK + gi) * 4;
      b0 = oboxw[a4 + 0]; b1 = oboxw[a4 + 1]; b2 = oboxw[a4 + 2]; b3 = oboxw[a4 + 3];
      kp = (valw[n * TOPK + gi] != 0) ? 1 : 0;
      ar = __fmul_rn(fmaxf(__fsub_rn(b2, b0), 0.0f), fmaxf(__fsub_rn(b3, b1), 0.0f));
    }
    for (int i = 0; i + 1 < (int)kcnt; ++i){
      int alive = __shfl(kp, i);
      float xi0 = __shfl(b0, i), xi1 = __shfl(b1, i), xi2 = __shfl(b2, i), xi3 = __shfl(b3, i);
      float ai = __shfl(ar, i);
      if (alive && L > i && kp){
        float ltx = fmaxf(xi0, b0), lty = fmaxf(xi1, b1);
        float rbx = fminf(xi2, b2), rby = fminf(xi3, b3);
        float w = fmaxf(__fsub_rn(rbx, ltx), 0.0f);
        float h = fmaxf(__fsub_rn(rby, lty), 0.0f);
        float inter = __fmul_rn(w, h);
        float den = __fadd_rn(__fsub_rn(__fadd_rn(ai, ar), inter), 1e-9f);
        if (inter / den > 0.6f) kp = 0;
      }
    }
    if (L < (int)kcnt) keepw[n * TOPK + gi] = (uint32_t)kp;
  } else if (L == 0){
    // slow path (kcnt > 64): sequential, correctness-only (statistically never hit)
    for (uint32_t i = 0; i < kcnt; ++i){
      int gi = (int)list[i];
      keepw[n * TOPK + gi] = valw[n * TOPK + gi];
    }
    for (uint32_t i = 0; i < kcnt; ++i){
      int gi = (int)list[i];
      if (!keepw[n * TOPK + gi]) continue;
      size_t a4 = ((size_t)n * TOPK + gi) * 4;
      float x0 = oboxw[a4], x1 = oboxw[a4 + 1], x2 = oboxw[a4 + 2], x3 = oboxw[a4 + 3];
      float ai = __fmul_rn(fmaxf(__fsub_rn(x2, x0), 0.0f), fmaxf(__fsub_rn(x3, x1), 0.0f));
      for (uint32_t j = i + 1; j < kcnt; ++j){
        int gj = (int)list[j];
        if (!keepw[n * TOPK + gj]) continue;
        size_t c4 = ((size_t)n * TOPK + gj) * 4;
        float y0 = oboxw[c4], y1 = oboxw[c4 + 1], y2 = oboxw[c4 + 2], y3 = oboxw[c4 + 3];
        float aj = __fmul_rn(fmaxf(__fsub_rn(y2, y0), 0.0f), fmaxf(__fsub_rn(y3, y1), 0.0f));
        float ltx = fmaxf(x0, y0), lty = fmaxf(x1, y1);
        float rbx = fminf(x2, y2), rby = fminf(x3, y3);
        float w = fmaxf(__fsub_rn(rbx, ltx), 0.0f);
        float h = fmaxf(__fsub_rn(rby, lty), 0.0f);
        float inter = __fmul_rn(w, h);
        float den = __fadd_rn(__fsub_rn(__fadd_rn(ai, aj), inter), 1e-9f);
        if (inter / den > 0.6f) keepw[n * TOPK + gj] = 0;
      }
    }
  }
}

// parallel compaction of kept (score-sorted) entries; first 100 rows, rest zero
__global__ void __launch_bounds__(256)
k_final(const uint32_t* __restrict__ keepw, const float* __restrict__ boxw,
        const uint32_t* __restrict__ labw, const float* __restrict__ scw,
        float* __restrict__ out){
  const int n = blockIdx.x;
  const int t = threadIdx.x;
  __shared__ uint32_t part[256];
  uint32_t f[4]; uint32_t cl = 0;
  const int base = t * 4;
  #pragma unroll
  for (int q = 0; q < 4; ++q){
    int i = base + q;
    f[q] = (i < TOPK) ? keepw[n * TOPK + i] : 0u;
    cl += (f[q] ? 1u : 0u);
  }
  part[t] = cl;
  __syncthreads();
  if (t == 0){
    uint32_t a = 0;
    for (int i = 0; i < 256; ++i){ uint32_t v = part[i]; part[i] = a; a += v; }
  }
  __syncthreads();
  float* outn = out + (size_t)n * POSTK * 6;
  for (int i = t; i < POSTK * 6; i += 256) outn[i] = 0.0f;
  __syncthreads();
  uint32_t off = part[t];
  #pragma unroll
  for (int q = 0; q < 4; ++q){
    int i = base + q;
    if (i < TOPK && f[q]){
      if (off < POSTK){
        float* row = outn + (size_t)off * 6;
        size_t b4 = ((size_t)n * TOPK + i) * 4;
        row[0] = boxw[b4]; row[1] = boxw[b4 + 1]; row[2] = boxw[b4 + 2]; row[3] = boxw[b4 + 3];
        row[4] = (float)labw[n * TOPK + i]; row[5] = scw[n * TOPK + i];
      }
      off++;
    }
  }
}

extern "C" void kernel_launch(void* const* d_in, const int* in_sizes, int n_in,
                              void* d_out, int out_size, void* d_ws, size_t ws_size,
                              hipStream_t stream){
  const float* locations = (const float*)d_in[0];
  const float* box_cls   = (const float*)d_in[1];
  const float* box_reg   = (const float*)d_in[2];
  const float* ctr       = (const float*)d_in[3];
  const float* im_info   = (const float*)d_in[4];
  float* out = (float*)d_out;
  char* ws = (char*)d_ws;
  uint32_t* h1    = (uint32_t*)(ws + B_H1);
  uint32_t* cnt   = (uint32_t*)(ws + B_CNT);
  uint32_t* done  = (uint32_t*)(ws + B_DONE);
  uint32_t* meta  = (uint32_t*)(ws + B_META);
  float*    sigc  = (float*)(ws + B_SIGC);
  uint64_t* cand  = (uint64_t*)(ws + B_CAND);
  float*    boxw  = (float*)(ws + B_BOX);
  float*    oboxw = (float*)(ws + B_OBOX);
  float*    scw   = (float*)(ws + B_SC);
  uint32_t* valw  = (uint32_t*)(ws + B_VAL);
  uint32_t* labw  = (uint32_t*)(ws + B_LAB);
  uint32_t* keepw = (uint32_t*)(ws + B_KEEP);

  hipMemsetAsync(d_ws, 0, B_ZEND, stream);
  k_prep<<<(NIMG * NPTS + 255) / 256, 256, 0, stream>>>(ctr, sigc);
  dim3 scang(BPI, NIMG);
  k_hist<<<scang, 256, 0, stream>>>(box_cls, sigc, h1, done, meta);
  k_collect<<<scang, 256, 0, stream>>>(box_cls, sigc, meta, cnt, cand);
  k_sort_decode<<<NIMG, 1024, 0, stream>>>(cnt, cand, locations, box_reg, im_info,
                                           boxw, oboxw, scw, valw, labw);
  k_nms<<<dim3(NCLS, NIMG), 64, 0, stream>>>(labw, oboxw, valw, keepw);
  k_final<<<NIMG, 256, 0, stream>>>(keepw, boxw, labw, scw, out);
}

// Round 5
// 379.349 us; speedup vs baseline: 1.0286x; 1.0133x over previous
//
#include <hip/hip_runtime.h>
#include <hip/hip_cooperative_groups.h>
#include <stdint.h>

namespace cg = cooperative_groups;

#define NIMG 8
#define NCLS 80
#define HF 100
#define WF 152
#define NPTS (HF*WF)          // 15200
#define NPC (NPTS*NCLS)       // 1216000
#define IMG_GROUPS (NPC/4)    // 304000 float4 groups per image
#define GPT 20                // float4 groups per thread (80 elems)
#define GPBLK (256*GPT)       // 5120 groups per block
#define BPI_S ((IMG_GROUPS + GPBLK - 1) / GPBLK)   // 60 blocks per image
#define GRID_S (BPI_S*NIMG)   // 480 blocks (needs only 2 blocks/CU co-resident)
#define NCU 256
#define TOPK 1000
#define CAP 2048
#define POSTK 100
// fallback (non-coop) pipeline constants, proven in R3
#define GPB_F 2048
#define BPI_F ((IMG_GROUPS + GPB_F - 1) / GPB_F)   // 149

// ---- workspace layout (bytes) ----
static constexpr size_t B_H1    = 0;                           // u32 [8][4096]
static constexpr size_t B_H2    = B_H1 + (size_t)8*4096*4;     // u32 [8][4096]
static constexpr size_t B_CNT   = B_H2 + (size_t)8*4096*4;     // u32 [8]
static constexpr size_t B_DONE  = B_CNT + 8*4;                 // u32 [8]
static constexpr size_t B_META  = B_DONE + 8*4;                // u32 [8][4]
static constexpr size_t B_ZEND  = B_META + 8*4*4;              // memset 0 through here
static constexpr size_t B_SIGC  = (B_ZEND + 15) & ~(size_t)15; // f32 [8][NPTS] (fallback)
static constexpr size_t B_CAND  = B_SIGC + (size_t)8*NPTS*4;   // u64 [8][CAP]
static constexpr size_t B_BOX   = B_CAND + (size_t)8*CAP*8;    // f32 [8][TOPK][4]
static constexpr size_t B_OBOX  = B_BOX + (size_t)8*TOPK*16;   // f32 [8][TOPK][4]
static constexpr size_t B_SC    = B_OBOX + (size_t)8*TOPK*16;  // f32 [8][TOPK]
static constexpr size_t B_VAL   = B_SC + (size_t)8*TOPK*4;     // u32 [8][TOPK]
static constexpr size_t B_LAB   = B_VAL + (size_t)8*TOPK*4;    // u32 [8][TOPK]
static constexpr size_t B_KEEP  = B_LAB + (size_t)8*TOPK*4;    // u32 [8][TOPK]

__device__ __forceinline__ float sigm(float x){ return 1.0f / (1.0f + expf(-x)); }

__device__ __forceinline__ void decode_one(int sn, int t, uint64_t kk,
    const float* __restrict__ locations, const float* __restrict__ box_reg,
    const float* __restrict__ im_info,
    float* __restrict__ boxw, float* __restrict__ oboxw, float* __restrict__ scw,
    uint32_t* __restrict__ valw, uint32_t* __restrict__ labw){
  uint32_t bits = (uint32_t)(kk >> 32);
  uint32_t fi = 0xFFFFFFFFu - (uint32_t)(kk & 0xFFFFFFFFull);
  float v = __uint_as_float(bits);
  int loc = 0, ci = 0;
  if (v > 0.0f){ loc = (int)(fi / NCLS); ci = (int)(fi - (uint32_t)loc * NCLS); }
  float px = locations[2 * loc], py = locations[2 * loc + 1];
  const float* rg = box_reg + (size_t)sn * 4 * NPTS;
  float rl = rg[loc], rt = rg[NPTS + loc], rr = rg[2 * NPTS + loc], rb = rg[3 * NPTS + loc];
  float h_im = im_info[sn * 2 + 0], w_im = im_info[sn * 2 + 1];
  float x1 = fminf(fmaxf(px - rl, 0.0f), w_im - 1.0f);
  float y1 = fminf(fmaxf(py - rt, 0.0f), h_im - 1.0f);
  float x2 = fminf(fmaxf(px + rr, 0.0f), w_im - 1.0f);
  float y2 = fminf(fmaxf(py + rb, 0.0f), h_im - 1.0f);
  bool valid = (v > 0.0f) && (__fsub_rn(x2, x1) >= 0.0f) && (__fsub_rn(y2, y1) >= 0.0f);
  float scv = valid ? v : 0.0f;
  float lab = (float)(ci + 1);
  float off = __fmul_rn(lab, 100000.0f);   // CLASS_OFFSET, mul then add (no fma) like ref
  size_t b4 = ((size_t)sn * TOPK + t) * 4;
  boxw[b4 + 0] = x1; boxw[b4 + 1] = y1; boxw[b4 + 2] = x2; boxw[b4 + 3] = y2;
  oboxw[b4 + 0] = __fadd_rn(x1, off); oboxw[b4 + 1] = __fadd_rn(y1, off);
  oboxw[b4 + 2] = __fadd_rn(x2, off); oboxw[b4 + 3] = __fadd_rn(y2, off);
  size_t b1 = (size_t)sn * TOPK + t;
  scw[b1] = scv; valw[b1] = valid ? 1u : 0u; labw[b1] = (uint32_t)(ci + 1);
}

// =================== cooperative single-sweep path ===================
__global__ void __launch_bounds__(256, 2)
k_select(const float* __restrict__ box_cls, const float* __restrict__ ctr,
         const float* __restrict__ locations, const float* __restrict__ box_reg,
         const float* __restrict__ im_info,
         uint32_t* __restrict__ h1, uint32_t* __restrict__ h2,
         uint32_t* __restrict__ cnt, uint64_t* __restrict__ cand,
         float* __restrict__ boxw, float* __restrict__ oboxw, float* __restrict__ scw,
         uint32_t* __restrict__ valw, uint32_t* __restrict__ labw){
  cg::grid_group grid = cg::this_grid();
  __shared__ alignas(16) uint32_t shist[4096];   // reused as u64[2048] for sort
  __shared__ uint32_t spsum[256];
  __shared__ uint32_t ssuff[256];
  __shared__ uint32_t sB, sCab, sT24;
  const int tid = threadIdx.x;
  const int n   = blockIdx.x / BPI_S;
  const int blk = blockIdx.x % BPI_S;

  // ---- phase A: single sweep; both sigmoids inline (ctr is read-only input) ----
  for (int i = tid; i < 4096; i += 256) shist[i] = 0;
  __syncthreads();
  const float4* cls4 = (const float4*)(box_cls + (size_t)n * NPC);
  const float*  ctn  = ctr + (size_t)n * NPTS;
  float sv[GPT * 4];
  #pragma unroll
  for (int c = 0; c < GPT / 2; ++c){
    int g0 = blk * GPBLK + c * 512 + tid;
    int g1 = g0 + 256;
    bool ok0 = (g0 < IMG_GROUPS), ok1 = (g1 < IMG_GROUPS);
    int cg0 = ok0 ? g0 : 0, cg1 = ok1 ? g1 : 0;
    float4 x0 = cls4[cg0];
    float4 x1 = cls4[cg1];
    int e0 = cg0 * 4, e1 = cg1 * 4;
    int ci0 = e0 / NPTS, ci1 = e1 / NPTS;
    int p0 = e0 - ci0 * NPTS, p1 = e1 - ci1 * NPTS;
    float4 y0 = *(const float4*)(ctn + p0);
    float4 y1 = *(const float4*)(ctn + p1);
    float xa[8] = {x0.x, x0.y, x0.z, x0.w, x1.x, x1.y, x1.z, x1.w};
    float ya[8] = {y0.x, y0.y, y0.z, y0.w, y1.x, y1.y, y1.z, y1.w};
    #pragma unroll
    for (int q = 0; q < 8; ++q){
      bool ok = (q < 4) ? ok0 : ok1;
      float a = sigm(xa[q]);
      float v = (a > 0.05f) ? a * sigm(ya[q]) : 0.0f;
      if (!ok) v = 0.0f;
      sv[c * 8 + q] = v;
      if (v > 0.0f) atomicAdd(&shist[__float_as_uint(v) >> 20], 1u);
    }
  }
  __syncthreads();
  {
    uint32_t* g1p = h1 + (size_t)n * 4096;
    for (int i = tid; i < 4096; i += 256){
      uint32_t v = shist[i];
      if (v) atomicAdd(&g1p[i], v);
    }
  }
  __threadfence();
  grid.sync();   // #1: level-1 histogram complete

  // ---- phase B: scan h1 -> B1, c_above; level-2 hist from registers ----
  {
    const uint32_t* h = h1 + (size_t)n * 4096;
    uint32_t hv[16];
    uint32_t s = 0;
    #pragma unroll
    for (int i = 0; i < 16; ++i){
      hv[i] = __hip_atomic_load(&h[tid * 16 + i], __ATOMIC_RELAXED, __HIP_MEMORY_SCOPE_AGENT);
      s += hv[i];
    }
    spsum[tid] = s;
    if (tid == 0){ sB = 0u; sCab = 0u; }
    __syncthreads();
    if (tid == 0){
      uint32_t a = 0;
      for (int seg = 255; seg >= 0; --seg){ ssuff[seg] = a; a += spsum[seg]; }
    }
    __syncthreads();
    if (ssuff[tid] < TOPK && ssuff[tid] + spsum[tid] >= TOPK){
      uint32_t a = ssuff[tid];
      for (int b = 15; b >= 0; --b){
        uint32_t hb = hv[b];
        if (a + hb >= TOPK){ sCab = a; sB = (uint32_t)(tid * 16 + b); break; }
        a += hb;
      }
    }
    __syncthreads();
  }
  const uint32_t B1 = sB;
  const uint32_t cab = sCab;
  for (int i = tid; i < 4096; i += 256) shist[i] = 0;
  __syncthreads();
  #pragma unroll
  for (int s = 0; s < GPT * 4; ++s){
    float v = sv[s];
    if (v > 0.0f){
      uint32_t bits = __float_as_uint(v);
      if ((bits >> 20) == B1) atomicAdd(&shist[(bits >> 8) & 4095u], 1u);
    }
  }
  __syncthreads();
  {
    uint32_t* g2p = h2 + (size_t)n * 4096;
    for (int i = tid; i < 4096; i += 256){
      uint32_t v = shist[i];
      if (v) atomicAdd(&g2p[i], v);
    }
  }
  __threadfence();
  grid.sync();   // #2: level-2 histogram complete

  // ---- phase C: scan h2 -> T24; collect candidates from registers ----
  {
    const uint32_t* h = h2 + (size_t)n * 4096;
    uint32_t hv[16];
    uint32_t s = 0;
    #pragma unroll
    for (int i = 0; i < 16; ++i){
      hv[i] = __hip_atomic_load(&h[tid * 16 + i], __ATOMIC_RELAXED, __HIP_MEMORY_SCOPE_AGENT);
      s += hv[i];
    }
    spsum[tid] = s;
    if (tid == 0) sT24 = (B1 << 12);
    __syncthreads();
    if (tid == 0){
      uint32_t a = 0;
      for (int seg = 255; seg >= 0; --seg){ ssuff[seg] = a; a += spsum[seg]; }
    }
    __syncthreads();
    const uint32_t R = TOPK - cab;
    if (ssuff[tid] < R && ssuff[tid] + spsum[tid] >= R){
      uint32_t a = ssuff[tid];
      for (int b = 15; b >= 0; --b){
        uint32_t hb = hv[b];
        if (a + hb >= R){ sT24 = (B1 << 12) | (uint32_t)(tid * 16 + b); break; }
        a += hb;
      }
    }
    __syncthreads();
  }
  const uint32_t T24 = sT24;
  {
    uint64_t* cd = cand + (size_t)n * CAP;
    #pragma unroll
    for (int s = 0; s < GPT * 4; ++s){
      float v = sv[s];
      if (v > 0.0f){
        uint32_t bits = __float_as_uint(v);
        if ((bits >> 8) >= T24){
          int c = s >> 3, hh = (s >> 2) & 1, q = s & 3;
          int g = blk * GPBLK + c * 512 + hh * 256 + tid;
          int e = g * 4 + q;
          int ci = e / NPTS;
          int p = e - ci * NPTS;
          uint32_t f = (uint32_t)(p * NCLS + ci);
          uint32_t pos = atomicAdd(&cnt[n], 1u);
          if (pos < CAP){
            uint64_t key = ((uint64_t)bits << 32) | (uint64_t)(0xFFFFFFFFu - f);
            __hip_atomic_store(&cd[pos], key, __ATOMIC_RELAXED, __HIP_MEMORY_SCOPE_AGENT);
          }
        }
      }
    }
  }
  __threadfence();
  grid.sync();   // #3: candidates complete

  // ---- phase D: blocks 0..7 bitonic-sort 2048 + decode ----
  if (blockIdx.x >= NIMG) return;
  const int sn = blockIdx.x;
  uint64_t* key = (uint64_t*)shist;
  int ncd = (int)__hip_atomic_load(&cnt[sn], __ATOMIC_RELAXED, __HIP_MEMORY_SCOPE_AGENT);
  if (ncd > CAP) ncd = CAP;
  {
    const uint64_t* cd = cand + (size_t)sn * CAP;
    #pragma unroll
    for (int m = 0; m < 8; ++m){
      int i = m * 256 + tid;
      key[i] = (i < ncd)
        ? __hip_atomic_load(&cd[i], __ATOMIC_RELAXED, __HIP_MEMORY_SCOPE_AGENT) : 0ull;
    }
  }
  __syncthreads();
  for (int k = 2; k <= 2048; k <<= 1){
    for (int j = k >> 1; j > 0; j >>= 1){
      #pragma unroll
      for (int m = 0; m < 8; ++m){
        int i = m * 256 + tid;
        int ixj = i ^ j;
        if (ixj > i){
          uint64_t a = key[i], b = key[ixj];
          bool desc = ((i & k) == 0);
          bool sw = desc ? (a < b) : (a > b);
          if (sw){ key[i] = b; key[ixj] = a; }
        }
      }
      __syncthreads();
    }
  }
  for (int m = 0; m < 4; ++m){
    int t = m * 256 + tid;
    if (t >= TOPK) break;
    decode_one(sn, t, key[t], locations, box_reg, im_info, boxw, oboxw, scw, valw, labw);
  }
}

// =================== fallback (non-coop) pipeline — proven in R3 ===================
__global__ void k_prep(const float* __restrict__ ctr, float* __restrict__ sigc){
  int i = blockIdx.x * 256 + threadIdx.x;
  if (i < NIMG * NPTS) sigc[i] = sigm(ctr[i]);
}

__global__ void __launch_bounds__(256)
k_hist_f(const float* __restrict__ box_cls, const float* __restrict__ sigc,
         uint32_t* __restrict__ h1, uint32_t* __restrict__ done, uint32_t* __restrict__ meta){
  __shared__ uint32_t h[4096];
  for (int i = threadIdx.x; i < 4096; i += 256) h[i] = 0;
  __syncthreads();
  const int n = blockIdx.y;
  const int tid = threadIdx.x;
  const float4* cls4 = (const float4*)(box_cls + (size_t)n * NPC);
  const float* sc_im = sigc + (size_t)n * NPTS;
  float4 xc[8], xs[8];
  bool ok[8];
  #pragma unroll
  for (int j = 0; j < 8; ++j){
    int graw = blockIdx.x * GPB_F + j * 256 + tid;
    ok[j] = (graw < IMG_GROUPS);
    int g = ok[j] ? graw : (IMG_GROUPS - 1);
    xc[j] = cls4[g];
    int e = g * 4; int c = e / NPTS; int p = e - c * NPTS;
    xs[j] = *(const float4*)(sc_im + p);
  }
  #pragma unroll
  for (int j = 0; j < 8; ++j){
    if (ok[j]){
      float sx[4] = {xc[j].x, xc[j].y, xc[j].z, xc[j].w};
      float cx[4] = {xs[j].x, xs[j].y, xs[j].z, xs[j].w};
      #pragma unroll
      for (int q = 0; q < 4; ++q){
        float scls = sigm(sx[q]);
        if (scls > 0.05f){
          float s = scls * cx[q];
          if (s > 0.0f) atomicAdd(&h[__float_as_uint(s) >> 20], 1u);
        }
      }
    }
  }
  __syncthreads();
  uint32_t* g1 = h1 + (size_t)n * 4096;
  for (int i = tid; i < 4096; i += 256){
    uint32_t v = h[i];
    if (v) atomicAdd(&g1[i], v);
  }
  __threadfence();
  __shared__ uint32_t last;
  if (tid == 0){
    uint32_t prev = __hip_atomic_fetch_add(&done[n], 1u, __ATOMIC_ACQ_REL,
                                           __HIP_MEMORY_SCOPE_AGENT);
    last = (prev == (uint32_t)(BPI_F - 1)) ? 1u : 0u;
  }
  __syncthreads();
  if (!last) return;
  __shared__ uint32_t psum[256];
  __shared__ uint32_t suff[256];
  uint32_t hv[16];
  uint32_t s = 0;
  #pragma unroll
  for (int i = 0; i < 16; ++i){
    hv[i] = __hip_atomic_load(&g1[tid * 16 + i], __ATOMIC_RELAXED, __HIP_MEMORY_SCOPE_AGENT);
    s += hv[i];
  }
  psum[tid] = s;
  __syncthreads();
  if (tid == 0){
    uint32_t a = 0;
    for (int seg = 255; seg >= 0; --seg){ suff[seg] = a; a += psum[seg]; }
  }
  __syncthreads();
  if (suff[tid] < TOPK && suff[tid] + psum[tid] >= TOPK){
    uint32_t a = suff[tid];
    for (int b = 15; b >= 0; --b){
      uint32_t hb = hv[b];
      if (a + hb >= TOPK){
        meta[n * 4 + 0] = a;
        meta[n * 4 + 1] = (uint32_t)(tid * 16 + b);
        break;
      }
      a += hb;
    }
  }
}

__global__ void __launch_bounds__(256)
k_collect_f(const float* __restrict__ box_cls, const float* __restrict__ sigc,
            const uint32_t* __restrict__ meta,
            uint32_t* __restrict__ cnt, uint64_t* __restrict__ cand){
  const int n = blockIdx.y;
  const int tid = threadIdx.x;
  const uint32_t B = meta[n * 4 + 1];
  const float4* cls4 = (const float4*)(box_cls + (size_t)n * NPC);
  const float* sc_im = sigc + (size_t)n * NPTS;
  uint64_t* cd = cand + (size_t)n * CAP;
  float4 xc[8], xs[8];
  bool ok[8];
  int pp[8], cc[8];
  #pragma unroll
  for (int j = 0; j < 8; ++j){
    int graw = blockIdx.x * GPB_F + j * 256 + tid;
    ok[j] = (graw < IMG_GROUPS);
    int g = ok[j] ? graw : (IMG_GROUPS - 1);
    xc[j] = cls4[g];
    int e = g * 4; int c = e / NPTS; int p = e - c * NPTS;
    pp[j] = p; cc[j] = c;
    xs[j] = *(const float4*)(sc_im + p);
  }
  #pragma unroll
  for (int j = 0; j < 8; ++j){
    if (ok[j]){
      float sx[4] = {xc[j].x, xc[j].y, xc[j].z, xc[j].w};
      float cx[4] = {xs[j].x, xs[j].y, xs[j].z, xs[j].w};
      #pragma unroll
      for (int q = 0; q < 4; ++q){
        float scls = sigm(sx[q]);
        if (scls > 0.05f){
          float s = scls * cx[q];
          if (s > 0.0f){
            uint32_t bits = __float_as_uint(s);
            if ((bits >> 20) >= B){
              uint32_t f = (uint32_t)((pp[j] + q) * NCLS + cc[j]);
              uint32_t pos = atomicAdd(&cnt[n], 1u);
              if (pos < CAP)
                cd[pos] = ((uint64_t)bits << 32) | (uint64_t)(0xFFFFFFFFu - f);
            }
          }
        }
      }
    }
  }
}

__global__ void __launch_bounds__(1024)
k_sort_decode(const uint32_t* __restrict__ cnt, const uint64_t* __restrict__ cand,
              const float* __restrict__ locations, const float* __restrict__ box_reg,
              const float* __restrict__ im_info,
              float* __restrict__ boxw, float* __restrict__ oboxw, float* __restrict__ scw,
              uint32_t* __restrict__ valw, uint32_t* __restrict__ labw){
  __shared__ uint64_t key[2048];
  const int n = blockIdx.x;
  const int t = threadIdx.x;
  int nc = (int)cnt[n]; if (nc > CAP) nc = CAP;
  const uint64_t* cd = cand + (size_t)n * CAP;
  key[t]        = (t < nc) ? cd[t] : 0ull;
  key[t + 1024] = (t + 1024 < nc) ? cd[t + 1024] : 0ull;
  __syncthreads();
  for (int k = 2; k <= 2048; k <<= 1){
    for (int j = k >> 1; j > 0; j >>= 1){
      #pragma unroll
      for (int m = 0; m < 2; ++m){
        int i = t + m * 1024;
        int ixj = i ^ j;
        if (ixj > i){
          uint64_t a = key[i], b = key[ixj];
          bool desc = ((i & k) == 0);
          bool sw = desc ? (a < b) : (a > b);
          if (sw){ key[i] = b; key[ixj] = a; }
        }
      }
      __syncthreads();
    }
  }
  if (t < TOPK)
    decode_one(n, t, key[t], locations, box_reg, im_info, boxw, oboxw, scw, valw, labw);
}

// =================== shared tail: per-class NMS + compaction ===================
__global__ void __launch_bounds__(64)
k_nms(const uint32_t* __restrict__ labw, const float* __restrict__ oboxw,
      const uint32_t* __restrict__ valw, uint32_t* __restrict__ keepw){
  const int n = blockIdx.y;
  const int c = blockIdx.x;
  const int L = threadIdx.x;
  __shared__ uint16_t list[TOPK];
  const uint32_t* lw = labw + (size_t)n * TOPK;
  uint32_t run = 0;
  #pragma unroll
  for (int j = 0; j < (TOPK + 63) / 64; ++j){
    int idx = j * 64 + L;
    bool m = (idx < TOPK) && (lw[idx] == (uint32_t)(c + 1));
    unsigned long long mask = __ballot(m);
    if (m){
      int pos = (int)run + __popcll(mask & ((1ull << L) - 1ull));
      list[pos] = (uint16_t)idx;
    }
    run += (uint32_t)__popcll(mask);
  }
  __syncthreads();
  const uint32_t kcnt = run;
  if (kcnt == 0) return;
  if (kcnt <= 64){
    int gi = 0, kp = 0;
    float b0 = 0, b1 = 0, b2 = 0, b3 = 0, ar = 0;
    if (L < (int)kcnt){
      gi = (int)list[L];
      size_t a4 = ((size_t)n * TOPK + gi) * 4;
      b0 = oboxw[a4 + 0]; b1 = oboxw[a4 + 1]; b2 = oboxw[a4 + 2]; b3 = oboxw[a4 + 3];
      kp = (valw[n * TOPK + gi] != 0) ? 1 : 0;
      ar = __fmul_rn(fmaxf(__fsub_rn(b2, b0), 0.0f), fmaxf(__fsub_rn(b3, b1), 0.0f));
    }
    for (int i = 0; i + 1 < (int)kcnt; ++i){
      int alive = __shfl(kp, i);
      float xi0 = __shfl(b0, i), xi1 = __shfl(b1, i), xi2 = __shfl(b2, i), xi3 = __shfl(b3, i);
      float ai = __shfl(ar, i);
      if (alive && L > i && kp){
        float ltx = fmaxf(xi0, b0), lty = fmaxf(xi1, b1);
        float rbx = fminf(xi2, b2), rby = fminf(xi3, b3);
        float w = fmaxf(__fsub_rn(rbx, ltx), 0.0f);
        float h = fmaxf(__fsub_rn(rby, lty), 0.0f);
        float inter = __fmul_rn(w, h);
        float den = __fadd_rn(__fsub_rn(__fadd_rn(ai, ar), inter), 1e-9f);
        if (inter / den > 0.6f) kp = 0;
      }
    }
    if (L < (int)kcnt) keepw[n * TOPK + gi] = (uint32_t)kp;
  } else if (L == 0){
    for (uint32_t i = 0; i < kcnt; ++i){
      int gi = (int)list[i];
      keepw[n * TOPK + gi] = valw[n * TOPK + gi];
    }
    for (uint32_t i = 0; i < kcnt; ++i){
      int gi = (int)list[i];
      if (!keepw[n * TOPK + gi]) continue;
      size_t a4 = ((size_t)n * TOPK + gi) * 4;
      float x0 = oboxw[a4], x1 = oboxw[a4 + 1], x2 = oboxw[a4 + 2], x3 = oboxw[a4 + 3];
      float ai = __fmul_rn(fmaxf(__fsub_rn(x2, x0), 0.0f), fmaxf(__fsub_rn(x3, x1), 0.0f));
      for (uint32_t j = i + 1; j < kcnt; ++j){
        int gj = (int)list[j];
        if (!keepw[n * TOPK + gj]) continue;
        size_t c4 = ((size_t)n * TOPK + gj) * 4;
        float y0 = oboxw[c4], y1 = oboxw[c4 + 1], y2 = oboxw[c4 + 2], y3 = oboxw[c4 + 3];
        float aj = __fmul_rn(fmaxf(__fsub_rn(y2, y0), 0.0f), fmaxf(__fsub_rn(y3, y1), 0.0f));
        float ltx = fmaxf(x0, y0), lty = fmaxf(x1, y1);
        float rbx = fminf(x2, y2), rby = fminf(x3, y3);
        float w = fmaxf(__fsub_rn(rbx, ltx), 0.0f);
        float h = fmaxf(__fsub_rn(rby, lty), 0.0f);
        float inter = __fmul_rn(w, h);
        float den = __fadd_rn(__fsub_rn(__fadd_rn(ai, aj), inter), 1e-9f);
        if (inter / den > 0.6f) keepw[n * TOPK + gj] = 0;
      }
    }
  }
}

__global__ void __launch_bounds__(256)
k_final(const uint32_t* __restrict__ keepw, const float* __restrict__ boxw,
        const uint32_t* __restrict__ labw, const float* __restrict__ scw,
        float* __restrict__ out){
  const int n = blockIdx.x;
  const int t = threadIdx.x;
  __shared__ uint32_t part[256];
  uint32_t f[4]; uint32_t cl = 0;
  const int base = t * 4;
  #pragma unroll
  for (int q = 0; q < 4; ++q){
    int i = base + q;
    f[q] = (i < TOPK) ? keepw[n * TOPK + i] : 0u;
    cl += (f[q] ? 1u : 0u);
  }
  part[t] = cl;
  __syncthreads();
  if (t == 0){
    uint32_t a = 0;
    for (int i = 0; i < 256; ++i){ uint32_t v = part[i]; part[i] = a; a += v; }
  }
  __syncthreads();
  float* outn = out + (size_t)n * POSTK * 6;
  for (int i = t; i < POSTK * 6; i += 256) outn[i] = 0.0f;
  __syncthreads();
  uint32_t off = part[t];
  #pragma unroll
  for (int q = 0; q < 4; ++q){
    int i = base + q;
    if (i < TOPK && f[q]){
      if (off < POSTK){
        float* row = outn + (size_t)off * 6;
        size_t b4 = ((size_t)n * TOPK + i) * 4;
        row[0] = boxw[b4]; row[1] = boxw[b4 + 1]; row[2] = boxw[b4 + 2]; row[3] = boxw[b4 + 3];
        row[4] = (float)labw[n * TOPK + i]; row[5] = scw[n * TOPK + i];
      }
      off++;
    }
  }
}

extern "C" void kernel_launch(void* const* d_in, const int* in_sizes, int n_in,
                              void* d_out, int out_size, void* d_ws, size_t ws_size,
                              hipStream_t stream){
  const float* locations = (const float*)d_in[0];
  const float* box_cls   = (const float*)d_in[1];
  const float* box_reg   = (const float*)d_in[2];
  const float* ctr       = (const float*)d_in[3];
  const float* im_info   = (const float*)d_in[4];
  float* out = (float*)d_out;
  char* ws = (char*)d_ws;
  uint32_t* h1    = (uint32_t*)(ws + B_H1);
  uint32_t* h2    = (uint32_t*)(ws + B_H2);
  uint32_t* cnt   = (uint32_t*)(ws + B_CNT);
  uint32_t* done  = (uint32_t*)(ws + B_DONE);
  uint32_t* meta  = (uint32_t*)(ws + B_META);
  float*    sigc  = (float*)(ws + B_SIGC);
  uint64_t* cand  = (uint64_t*)(ws + B_CAND);
  float*    boxw  = (float*)(ws + B_BOX);
  float*    oboxw = (float*)(ws + B_OBOX);
  float*    scw   = (float*)(ws + B_SC);
  uint32_t* valw  = (uint32_t*)(ws + B_VAL);
  uint32_t* labw  = (uint32_t*)(ws + B_LAB);
  uint32_t* keepw = (uint32_t*)(ws + B_KEEP);

  hipMemsetAsync(d_ws, 0, B_ZEND, stream);

  // host-side, capture-safe, deterministic probe: can the coop grid be co-resident?
  int occ = 0;
  hipError_t oe = hipOccupancyMaxActiveBlocksPerMultiprocessor(&occ, k_select, 256, 0);
  bool use_coop = (oe == hipSuccess) && (occ * NCU >= GRID_S);

  if (use_coop){
    void* args[] = {
      (void*)&box_cls, (void*)&ctr, (void*)&locations, (void*)&box_reg, (void*)&im_info,
      (void*)&h1, (void*)&h2, (void*)&cnt, (void*)&cand,
      (void*)&boxw, (void*)&oboxw, (void*)&scw, (void*)&valw, (void*)&labw
    };
    hipLaunchCooperativeKernel((const void*)k_select, dim3(GRID_S), dim3(256),
                               args, 0, stream);
  } else {
    k_prep<<<(NIMG * NPTS + 255) / 256, 256, 0, stream>>>(ctr, sigc);
    dim3 scang(BPI_F, NIMG);
    k_hist_f<<<scang, 256, 0, stream>>>(box_cls, sigc, h1, done, meta);
    k_collect_f<<<scang, 256, 0, stream>>>(box_cls, sigc, meta, cnt, cand);
    k_sort_decode<<<NIMG, 1024, 0, stream>>>(cnt, cand, locations, box_reg, im_info,
                                             boxw, oboxw, scw, valw, labw);
  }
  k_nms<<<dim3(NCLS, NIMG), 64, 0, stream>>>(labw, oboxw, valw, keepw);
  k_final<<<NIMG, 256, 0, stream>>>(keepw, boxw, labw, scw, out);
}